// Round 12
// baseline (168.578 us; speedup 1.0000x reference)
//
#include <hip/hip_runtime.h>

// InfoNCE fwd+bwd on MI355X. 3-kernel pipeline.
// x (B=256, T=128, V=512) fp32, targets (B,T) int32, S=256.
// out[0] = total_loss, out[1:] = grad (B,T,V) fp32 (16,777,217 floats).

#define TT 128
#define VV 512
#define QSPLIT 8

typedef float f4 __attribute__((ext_vector_type(4)));

__device__ __forceinline__ float clip30(float v) {
  return fminf(fmaxf(v, -30.f), 30.f);
}

// raw barrier: orders LDS (lgkmcnt only) WITHOUT draining outstanding
// global stores (hipcc's __syncthreads emits s_waitcnt vmcnt(0) which
// serializes the NT store stream). sched_barrier fences per rule #18.
__device__ __forceinline__ void bar_lds() {
  asm volatile("s_waitcnt lgkmcnt(0)" ::: "memory");
  __builtin_amdgcn_sched_barrier(0);
  __builtin_amdgcn_s_barrier();
  __builtin_amdgcn_sched_barrier(0);
}

// ---------------------------------------------------------------------------
// Kernel A: terms partials, direct gather (no LDS, no barriers).
// grid = 2048 (b = bid&255, q = bid>>8), 256 threads (thread = s).
// ---------------------------------------------------------------------------
__global__ __launch_bounds__(256) void terms_kernel(
    const float* __restrict__ x, const int* __restrict__ tgt,
    float* __restrict__ partial) {
  int bid = blockIdx.x;
  int b = bid & 255, q = bid >> 8, s = threadIdx.x;
  int4 tg[4];
#pragma unroll
  for (int k = 0; k < 4; ++k)
    tg[k] = ((const int4*)(tgt + (size_t)s * TT + q * 16))[k];
  const float* xb = x + ((size_t)b * TT + q * 16) * VV;
  float a0 = 0.f, a1 = 0.f, a2 = 0.f, a3 = 0.f;
#pragma unroll
  for (int k = 0; k < 4; ++k) {
    a0 += clip30(xb[(4 * k + 0) * VV + tg[k].x]);
    a1 += clip30(xb[(4 * k + 1) * VV + tg[k].y]);
    a2 += clip30(xb[(4 * k + 2) * VV + tg[k].z]);
    a3 += clip30(xb[(4 * k + 3) * VV + tg[k].w]);
  }
  partial[(size_t)((q << 8) + b) * 256 + s] = (a0 + a1) + (a2 + a3);
}

// ---------------------------------------------------------------------------
// Kernel B: per-row softmax/logsumexp. grid = 256 (row), 256 threads (b).
// ---------------------------------------------------------------------------
__global__ __launch_bounds__(256) void softmax_kernel(
    const float* __restrict__ partial, float* __restrict__ coefT,
    float* __restrict__ losses) {
  int row = blockIdx.x, b = threadIdx.x;
  int w = b >> 6, lane = b & 63;
  float t = 0.f;
#pragma unroll
  for (int q = 0; q < QSPLIT; ++q)
    t += partial[(size_t)((q << 8) + b) * 256 + row];
  float m = t;
#pragma unroll
  for (int off = 32; off; off >>= 1) m = fmaxf(m, __shfl_xor(m, off));
  __shared__ float wm[4], ws[4];
  if (lane == 0) wm[w] = m;
  __syncthreads();
  m = fmaxf(fmaxf(wm[0], wm[1]), fmaxf(wm[2], wm[3]));
  float e = expf(t - m);
  float ssum = e;
#pragma unroll
  for (int off = 32; off; off >>= 1) ssum += __shfl_xor(ssum, off);
  if (lane == 0) ws[w] = ssum;
  __syncthreads();
  float sum = ws[0] + ws[1] + ws[2] + ws[3];
  coefT[(b << 8) + row] = (b == row ? 1.f : 0.f) - e / sum;
  if (b == row) losses[row] = (t - m) - logf(sum);
}

// ---------------------------------------------------------------------------
// Kernel C: grad scatter, pipelined streaming form.
// grid = 1024 blocks (exactly 4/CU, one generation), 256 threads.
// Block k handles tiles j = 4k..4k+3 (tile = 4096 floats = 8 t-rows of one
// b = k>>2). Double-buffered LDS; raw lgkm-only barriers so NT stores of
// tile i remain in flight during zero/scatter of tile i+1 -> continuous
// store stream per CU for the kernel's whole lifetime.
// Tile layout (proven round 5): out[j*4096+u]; u=0 = grad flat (j*4096-1)
// (row j*8-1, v=511) or total loss (j==0); u>=1 = grad flat j*4096-1+u;
// pad slot [4096] discarded except j==4095 -> final element out[2^24].
// ---------------------------------------------------------------------------
__global__ __launch_bounds__(256) void grad_kernel(
    const float* __restrict__ coefT, const int* __restrict__ tgt,
    const float* __restrict__ losses, float* __restrict__ out) {
  int k = blockIdx.x, s = threadIdx.x;
  int w = s >> 6, lane = s & 63;
  int b = k >> 2;  // constant over the block's 4 tiles
  __shared__ __align__(16) float smem[2][4100];  // 2 x 16.4KB (16B-stride ok)
  __shared__ double dred[4];

  float c = coefT[(b << 8) + s];  // loaded once per block

#pragma unroll 1
  for (int seg = 0; seg < 4; ++seg) {
    int j = (k << 2) | seg;
    int t0 = (j & 15) << 3;
    int buf = seg & 1;
    float* tile = &smem[buf][0];
    f4* rz = (f4*)tile;

    // prefetch this tile's targets + boundary inputs (vm loads pipeline
    // freely across the raw barriers - no vmcnt drain anywhere)
    int4 tg0 = *(const int4*)(tgt + (size_t)s * TT + t0);
    int4 tg1 = *(const int4*)(tgt + (size_t)s * TT + t0 + 4);
    float bc = 0.f;
    double ls = 0.0;
    if (j > 0) {
      int R = (j << 3) - 1, th = R & 127, bh = R >> 7;
      float cb = c;
      if (bh != b) cb = coefT[(bh << 8) + s];  // rare (seg==0 && k%4==0)
      if (tgt[(size_t)s * TT + th] == VV - 1) bc = cb;
    } else {
      ls = (double)losses[s];
    }

    // zero phase
    f4 zero = {0.f, 0.f, 0.f, 0.f};
#pragma unroll
    for (int m = 0; m < 4; ++m) rz[s + m * 256] = zero;
    if (s == 0) tile[4096] = 0.f;
    bar_lds();  // B1: zeros visible; prev-tile NT stores still in flight

    // scatter phase: row r (8 rows), slot = 1 + r*512 + v
    atomicAdd(&tile[1 + 0 * VV + tg0.x], c);
    atomicAdd(&tile[1 + 1 * VV + tg0.y], c);
    atomicAdd(&tile[1 + 2 * VV + tg0.z], c);
    atomicAdd(&tile[1 + 3 * VV + tg0.w], c);
    atomicAdd(&tile[1 + 4 * VV + tg1.x], c);
    atomicAdd(&tile[1 + 5 * VV + tg1.y], c);
    atomicAdd(&tile[1 + 6 * VV + tg1.z], c);
    atomicAdd(&tile[1 + 7 * VV + tg1.w], c);
#pragma unroll
    for (int off = 32; off; off >>= 1) bc += __shfl_xor(bc, off);
    if (j > 0 && lane == 0) atomicAdd(&tile[0], bc);
    if (j == 0) {  // block 0, seg 0 only; block-uniform branch
#pragma unroll
      for (int off = 32; off; off >>= 1) ls += __shfl_xor(ls, off);
      if (lane == 0) dred[w] = ls;
      __syncthreads();  // no stores in flight yet for block 0 seg 0
      if (s == 0) tile[0] = (float)(dred[0] + dred[1] + dred[2] + dred[3]);
    }
    bar_lds();  // B2: scatter complete

    // store phase: 4 NT f4 per thread, fire and forget
    f4* go = (f4*)(out + (size_t)j * 4096);
#pragma unroll
    for (int m = 0; m < 4; ++m)
      __builtin_nontemporal_store(rz[s + m * 256], &go[s + m * 256]);
    if (j == 4095 && s == 0) out[(size_t)4096 * 4096] = tile[4096];
  }
}

extern "C" void kernel_launch(void* const* d_in, const int* in_sizes, int n_in,
                              void* d_out, int out_size, void* d_ws, size_t ws_size,
                              hipStream_t stream) {
  const float* x = (const float*)d_in[0];
  const int* tgt = (const int*)d_in[1];
  float* out = (float*)d_out;

  float* partial = (float*)d_ws;                  // 8*256*256 floats (2 MiB)
  float* coefT = partial + QSPLIT * 256 * 256;    // 256*256 floats
  float* losses = coefT + 256 * 256;              // 256 floats

  terms_kernel<<<dim3(2048), dim3(256), 0, stream>>>(x, tgt, partial);
  softmax_kernel<<<dim3(256), dim3(256), 0, stream>>>(partial, coefT, losses);
  grad_kernel<<<dim3(1024), dim3(256), 0, stream>>>(coefT, tgt, losses, out);
}